// Round 10
// baseline (411.338 us; speedup 1.0000x reference)
//
#include <hip/hip_runtime.h>
#include <cmath>

#define FINAL 112
#define HW    224
#define DIM   256
#define HW2   (HW*HW)       // 50176
#define F2    (FINAL*FINAL) // 12544

// Normalized separable 5-tap Gaussian, computed in double to match numpy
__device__ __forceinline__ void blur_weights(float fn[5]) {
    double fd[5]; double s = 0.0;
#pragma unroll
    for (int t = 0; t < 5; ++t) {
        double d = (double)(t - 2);
        fd[t] = exp(-1.4142135623730951 * d * d);
        s += fd[t];
    }
#pragma unroll
    for (int t = 0; t < 5; ++t) fn[t] = (float)(fd[t] / s);
}

// bf16 helpers. Pack via v_cvt_pk_bf16_f32 (gfx950 HW RTNE).
__device__ __forceinline__ unsigned int cvt_pk_bf16(float a, float b) {
    unsigned int r;
    asm("v_cvt_pk_bf16_f32 %0, %1, %2" : "=v"(r) : "v"(a), "v"(b));
    return r;
}
__device__ __forceinline__ float bflo(unsigned int q) { return __uint_as_float(q << 16); }
__device__ __forceinline__ float bfhi(unsigned int q) { return __uint_as_float(q & 0xffff0000u); }

// flag: 0=int32, 1=uint8, 2=float32, 3=int64
__device__ __forceinline__ float mask_val(const void* m, int flag, size_t idx) {
    if (flag == 0) return ((const int*)m)[idx] ? 1.0f : 0.0f;
    if (flag == 1) return ((const unsigned char*)m)[idx] ? 1.0f : 0.0f;
    if (flag == 2) return (((const float*)m)[idx] != 0.0f) ? 1.0f : 0.0f;
    return ((const long long*)m)[idx] ? 1.0f : 0.0f;
}

// fallback-path detect
__global__ void k_detect(const unsigned int* __restrict__ m, int* __restrict__ flag, int nwords) {
    __shared__ int s_b123, s_3f, s_oddnz;
    if (threadIdx.x == 0) { s_b123 = 0; s_3f = 0; s_oddnz = 0; }
    __syncthreads();
    int b123 = 0, c3f = 0, oddnz = 0;
    for (int i = threadIdx.x; i < nwords; i += blockDim.x) {
        unsigned int u = m[i];
        if (u & 0xFFFFFF00u) b123++;
        if ((u >> 24) == 0x3Fu) c3f++;
        if ((i & 1) && u) oddnz++;
    }
    if (b123) atomicAdd(&s_b123, b123);
    if (c3f) atomicAdd(&s_3f, c3f);
    if (oddnz) atomicAdd(&s_oddnz, oddnz);
    __syncthreads();
    if (threadIdx.x == 0) {
        int f;
        if (s_b123 == 0) f = (s_oddnz == 0) ? 3 : 0;
        else if (s_3f > nwords / 8) f = 2;
        else f = 1;
        *flag = f;
    }
}

// ---------------- fast path ----------------

__device__ __forceinline__ float4 f4fma(float a, float4 x, float4 y) {
    return make_float4(fmaf(a, x.x, y.x), fmaf(a, x.y, y.y),
                       fmaf(a, x.z, y.z), fmaf(a, x.w, y.w));
}

// Register-streaming separable blur: zero LDS, zero barriers. BW-bound.
__launch_bounds__(256)
__global__ void k_blur(const float* __restrict__ hr, unsigned short* __restrict__ blurh) {
    const int bc = blockIdx.x;
    const int w = threadIdx.x >> 6, lane = threadIdx.x & 63;
    const bool act = (lane < 56);
    float fn[5]; blur_weights(fn);
    const float4* src = (const float4*)(hr + (size_t)bc * HW2);
    unsigned short* dst = blurh + (size_t)bc * HW2;
    const int rbase = w * 56 - 2;

    float4 z = make_float4(0.f, 0.f, 0.f, 0.f);
    float4 w0 = z, w1 = z, w2 = z, w3 = z, w4 = z;

#pragma unroll
    for (int p = 0; p < 4; ++p) {
        const int g = rbase + p;
        float4 v = z;
        if (g >= 0 && g < HW && act) v = src[(size_t)g * 56 + lane];
        w0 = w1; w1 = w2; w2 = w3; w3 = w4; w4 = v;
    }

#pragma unroll 4
    for (int i = 4; i < 60; ++i) {
        const int g = rbase + i;
        float4 v = z;
        if (g < HW && act) v = src[(size_t)g * 56 + lane];   // g >= 2 here
        w0 = w1; w1 = w2; w2 = w3; w3 = w4; w4 = v;

        float4 vb = z;
        vb = f4fma(fn[0], w0, vb);
        vb = f4fma(fn[1], w1, vb);
        vb = f4fma(fn[2], w2, vb);
        vb = f4fma(fn[3], w3, vb);
        vb = f4fma(fn[4], w4, vb);

        float lz = __shfl_up(vb.z, 1), lw = __shfl_up(vb.w, 1);
        if (lane == 0) { lz = 0.f; lw = 0.f; }
        float rx = __shfl_down(vb.x, 1), ry = __shfl_down(vb.y, 1);
        float win[8] = { lz, lw, vb.x, vb.y, vb.z, vb.w, rx, ry };
        float o[4];
#pragma unroll
        for (int j = 0; j < 4; ++j) {
            float s = 0.f;
#pragma unroll
            for (int t = 0; t < 5; ++t) s = fmaf(fn[t], win[j + t], s);
            o[j] = s;
        }
        if (act) {
            uint2 pk; pk.x = cvt_pk_bf16(o[0], o[1]); pk.y = cvt_pk_bf16(o[2], o[3]);
            *(uint2*)(dst + (size_t)(g - 2) * HW + 4 * lane) = pk;
        }
    }
}

// Fused logits + softmax + output, split by output-column PARITY.
// Block = (b, oy, par): 8 waves x 32 channels. Lane l<56 owns ox = 2l+par;
// the SAME aligned uint2 row load serves both parities (even: {prev.w,x,y},
// odd: {y,z,w}), so each block does half the FMA with full-width loads.
// grid = 4*112*2 = 896 x 512.
__launch_bounds__(512, 1)
__global__ void k_fuse(const unsigned short* __restrict__ blurh,
                       const float* __restrict__ wk, const float* __restrict__ kb,
                       const float* __restrict__ lb, const void* __restrict__ mask,
                       float* __restrict__ out) {
    const int par = blockIdx.x & 1;
    const int rst = blockIdx.x >> 1;          // b*FINAL + oy
    const int oy = rst % FINAL, b = rst / FINAL;
    const int tid = threadIdx.x;
    const int wv = tid >> 6, lane = tid & 63;
    const bool act = (lane < 56);
    const int row0 = 2 * oy - 1;

    // mask-encoding detection from first 8KB (L2-broadcast)
    __shared__ int sb, sf, so;
    if (tid == 0) { sb = 0; sf = 0; so = 0; }
    __syncthreads();
    {
        const unsigned int* mw = (const unsigned int*)mask;
        int b123 = 0, c3f = 0, oddnz = 0;
        for (int i = tid; i < 2048; i += 512) {
            unsigned int u = mw[i];
            if (u & 0xFFFFFF00u) b123++;
            if ((u >> 24) == 0x3Fu) c3f++;
            if ((i & 1) && u) oddnz++;
        }
        if (b123) atomicAdd(&sb, b123);
        if (c3f) atomicAdd(&sf, c3f);
        if (oddnz) atomicAdd(&so, oddnz);
    }   // ordered by the barrier after phase A

    __shared__ float pl[8][9][56];
    __shared__ float sa[9][56];

    // ---- phase A: per-wave partial logits (32 channels, one parity) ----
    float acc[9];
#pragma unroll
    for (int o = 0; o < 9; ++o) acc[o] = 0.f;

#pragma unroll 2
    for (int k = 0; k < 32; ++k) {
        const int c = (wv << 5) + k;
        const unsigned short* base = blurh + ((size_t)(b * DIM + c)) * HW2;
        float t[3][3];
#pragma unroll
        for (int kh = 0; kh < 3; ++kh) {
            const int row = row0 + kh;
            uint2 q = make_uint2(0u, 0u);
            if (row >= 0 && act)
                q = *(const uint2*)(base + (size_t)row * HW + 4 * lane);
            float vx = bflo(q.x), vy = bfhi(q.x), vz = bflo(q.y), vw = bfhi(q.y);
            float pv = __shfl_up(vw, 1);
            if (lane == 0) pv = 0.f;
            if (par == 0) { t[kh][0] = pv; t[kh][1] = vx; t[kh][2] = vy; }
            else          { t[kh][0] = vy; t[kh][1] = vz; t[kh][2] = vw; }
        }
        const float* wc = wk + (size_t)c * 9;
#pragma unroll
        for (int o = 0; o < 9; ++o) {
            const float* wo = wc + (size_t)o * (DIM * 9);
#pragma unroll
            for (int kh = 0; kh < 3; ++kh)
#pragma unroll
                for (int j = 0; j < 3; ++j)
                    acc[o] = fmaf(wo[kh * 3 + j], t[kh][j], acc[o]);
        }
    }
    if (act) {
#pragma unroll
        for (int o = 0; o < 9; ++o) pl[wv][o][lane] = acc[o];
    }
    __syncthreads();

    int flag;
    if (sb == 0) flag = (so == 0) ? 3 : 0;
    else if (sf > 256) flag = 2;
    else flag = 1;

    // ---- reduce 8 waves + bias + mask (504 slots) ----
    for (int i = tid; i < 9 * 56; i += 512) {
        const int o = i / 56, x = i - o * 56;
        float s = 0.f;
#pragma unroll
        for (int g = 0; g < 8; ++g) s += pl[g][o][x];
        const int ox = 2 * x + par;
        size_t midx = (((size_t)b * 9 + o) * FINAL + oy) * FINAL + ox;
        pl[0][o][x] = (s + kb[o]) * mask_val(mask, flag, midx) + lb[o];
    }
    __syncthreads();

    // ---- softmax over 9 window positions ----
    if (tid < 56) {
        float l[9]; float mx = -3.4e38f;
#pragma unroll
        for (int o = 0; o < 9; ++o) { l[o] = pl[0][o][tid]; mx = fmaxf(mx, l[o]); }
        float sum = 0.f;
#pragma unroll
        for (int o = 0; o < 9; ++o) { l[o] = expf(l[o] - mx); sum += l[o]; }
        const float inv = 1.0f / sum;
#pragma unroll
        for (int o = 0; o < 9; ++o) sa[o][tid] = l[o] * inv;
    }
    __syncthreads();

    // ---- phase B: out[b,c,oy,2l+par] = sum_k attn_k * tap_k (rows L2-hot) ----
    float a[9];
#pragma unroll
    for (int o = 0; o < 9; ++o) a[o] = act ? sa[o][lane] : 0.f;

#pragma unroll 2
    for (int k = 0; k < 32; ++k) {
        const int c = (wv << 5) + k;
        const unsigned short* base = blurh + ((size_t)(b * DIM + c)) * HW2;
        float s = 0.f;
#pragma unroll
        for (int kh = 0; kh < 3; ++kh) {
            const int row = row0 + kh;
            uint2 q = make_uint2(0u, 0u);
            if (row >= 0 && act)
                q = *(const uint2*)(base + (size_t)row * HW + 4 * lane);
            float vx = bflo(q.x), vy = bfhi(q.x), vz = bflo(q.y), vw = bfhi(q.y);
            float pv = __shfl_up(vw, 1);
            if (lane == 0) pv = 0.f;
            float t0, t1, t2;
            if (par == 0) { t0 = pv; t1 = vx; t2 = vy; }
            else          { t0 = vy; t1 = vz; t2 = vw; }
            s = fmaf(a[kh * 3 + 0], t0, s);
            s = fmaf(a[kh * 3 + 1], t1, s);
            s = fmaf(a[kh * 3 + 2], t2, s);
        }
        if (act)
            out[((size_t)(b * DIM + c)) * F2 + (size_t)oy * FINAL + 2 * lane + par] = s;
    }
}

// ---------------- fallback path (round-1, known-correct) ----------------

__launch_bounds__(512, 1)
__global__ void k_logits_fb(const float* __restrict__ hr, const float* __restrict__ wk,
                            const float* __restrict__ kb, const float* __restrict__ lb,
                            const void* __restrict__ mask, const int* __restrict__ flagp,
                            float* __restrict__ attn) {
    const int blk = blockIdx.x;
    const int b = blk / FINAL, oy = blk % FINAL;
    const int tid = threadIdx.x;
    const int half = tid >> 8;
    const int lane = tid & 255;
    __shared__ float sIn[2][7][HW];
    __shared__ float sV[2][3][HW + 4];
    __shared__ float sB[2][3][HW + 2];
    __shared__ float sW[2][81];
    __shared__ float sL[1008];
    float fn[5]; blur_weights(fn);
    if (lane < 3) {
        sV[half][lane][0] = 0.f; sV[half][lane][1] = 0.f;
        sV[half][lane][HW + 2] = 0.f; sV[half][lane][HW + 3] = 0.f;
        sB[half][lane][0] = 0.f; sB[half][lane][HW + 1] = 0.f;
    }
    float acc0 = 0.f, acc1 = 0.f;
    const int s1 = tid + 512;
    const int o0 = tid / FINAL, x0 = tid % FINAL;
    const int o1 = s1 / FINAL, x1 = s1 % FINAL;
    const bool has1 = (s1 < 9 * FINAL);
    for (int c0 = 0; c0 < DIM; c0 += 2) {
        const int c = c0 + half;
        const float* src = hr + ((size_t)(b * DIM + c)) * HW2;
        for (int i = lane; i < 7 * HW; i += 256) {
            int r = i / HW, x = i - r * HW;
            int g = 2 * oy - 3 + r;
            sIn[half][r][x] = (g >= 0 && g < HW) ? src[(size_t)g * HW + x] : 0.f;
        }
        if (lane < 81) {
            int o = lane / 9, kk = lane - o * 9;
            sW[half][lane] = wk[((size_t)(o * DIM + c)) * 9 + kk];
        }
        __syncthreads();
        if (lane < HW) {
#pragma unroll
            for (int j = 0; j < 3; ++j) {
                int by = 2 * oy - 1 + j;
                float v = 0.f;
#pragma unroll
                for (int t = 0; t < 5; ++t) v = fmaf(fn[t], sIn[half][j + t][lane], v);
                sV[half][j][lane + 2] = (by >= 0 && by < HW) ? v : 0.f;
            }
        }
        __syncthreads();
        if (lane < HW) {
#pragma unroll
            for (int j = 0; j < 3; ++j) {
                float v = 0.f;
#pragma unroll
                for (int t = 0; t < 5; ++t) v = fmaf(fn[t], sV[half][j][lane + t], v);
                sB[half][j][lane + 1] = v;
            }
        }
        __syncthreads();
#pragma unroll
        for (int cc = 0; cc < 2; ++cc) {
            const float* wv_ = sW[cc];
            float a0 = 0.f;
#pragma unroll
            for (int kh = 0; kh < 3; ++kh)
#pragma unroll
                for (int kw = 0; kw < 3; ++kw)
                    a0 = fmaf(sB[cc][kh][2 * x0 + kw], wv_[o0 * 9 + kh * 3 + kw], a0);
            acc0 += a0;
            if (has1) {
                float a1v = 0.f;
#pragma unroll
                for (int kh = 0; kh < 3; ++kh)
#pragma unroll
                    for (int kw = 0; kw < 3; ++kw)
                        a1v = fmaf(sB[cc][kh][2 * x1 + kw], wv_[o1 * 9 + kh * 3 + kw], a1v);
                acc1 += a1v;
            }
        }
        __syncthreads();
    }
    sL[tid] = acc0;
    if (has1) sL[s1] = acc1;
    __syncthreads();
    if (tid < FINAL) {
        const int flag = *flagp;
        float l[9]; float mx = -3.4e38f;
#pragma unroll
        for (int o = 0; o < 9; ++o) {
            size_t midx = (((size_t)b * 9 + o) * FINAL + oy) * FINAL + tid;
            float patch = sL[o * FINAL + tid] + kb[o];
            float lo = patch * mask_val(mask, flag, midx) + lb[o];
            l[o] = lo;
            mx = fmaxf(mx, lo);
        }
        float sum = 0.f;
#pragma unroll
        for (int o = 0; o < 9; ++o) { l[o] = expf(l[o] - mx); sum += l[o]; }
        float inv = 1.0f / sum;
#pragma unroll
        for (int o = 0; o < 9; ++o)
            attn[(((size_t)b * 9 + o) * FINAL + oy) * FINAL + tid] = l[o] * inv;
    }
}

__launch_bounds__(512, 1)
__global__ void k_out_fb(const float* __restrict__ hr, const float* __restrict__ attn,
                         float* __restrict__ out) {
    const int blk = blockIdx.x;
    const int b = blk / FINAL, oy = blk % FINAL;
    const int tid = threadIdx.x;
    const int half = tid >> 8;
    const int lane = tid & 255;
    __shared__ float sIn[2][7][HW];
    __shared__ float sV[2][3][HW + 4];
    __shared__ float sB[2][3][HW + 2];
    __shared__ float sA[9][FINAL];
    float fn[5]; blur_weights(fn);
    if (lane < 3) {
        sV[half][lane][0] = 0.f; sV[half][lane][1] = 0.f;
        sV[half][lane][HW + 2] = 0.f; sV[half][lane][HW + 3] = 0.f;
        sB[half][lane][0] = 0.f; sB[half][lane][HW + 1] = 0.f;
    }
    for (int i = tid; i < 9 * FINAL; i += 512) {
        int o = i / FINAL, x = i - o * FINAL;
        sA[o][x] = attn[(((size_t)b * 9 + o) * FINAL + oy) * FINAL + x];
    }
    for (int c0 = 0; c0 < DIM; c0 += 2) {
        const int c = c0 + half;
        const float* src = hr + ((size_t)(b * DIM + c)) * HW2;
        for (int i = lane; i < 7 * HW; i += 256) {
            int r = i / HW, x = i - r * HW;
            int g = 2 * oy - 3 + r;
            sIn[half][r][x] = (g >= 0 && g < HW) ? src[(size_t)g * HW + x] : 0.f;
        }
        __syncthreads();
        if (lane < HW) {
#pragma unroll
            for (int j = 0; j < 3; ++j) {
                int by = 2 * oy - 1 + j;
                float v = 0.f;
#pragma unroll
                for (int t = 0; t < 5; ++t) v = fmaf(fn[t], sIn[half][j + t][lane], v);
                sV[half][j][lane + 2] = (by >= 0 && by < HW) ? v : 0.f;
            }
        }
        __syncthreads();
        if (lane < HW) {
#pragma unroll
            for (int j = 0; j < 3; ++j) {
                float v = 0.f;
#pragma unroll
                for (int t = 0; t < 5; ++t) v = fmaf(fn[t], sV[half][j][lane + t], v);
                sB[half][j][lane + 1] = v;
            }
        }
        __syncthreads();
        if (lane < FINAL) {
            float a = 0.f;
#pragma unroll
            for (int kh = 0; kh < 3; ++kh)
#pragma unroll
                for (int kw = 0; kw < 3; ++kw)
                    a = fmaf(sA[kh * 3 + kw][lane], sB[half][kh][2 * lane + kw], a);
            out[(((size_t)(b * DIM + c)) * FINAL + oy) * FINAL + lane] = a;
        }
    }
}

extern "C" void kernel_launch(void* const* d_in, const int* in_sizes, int n_in,
                              void* d_out, int out_size, void* d_ws, size_t ws_size,
                              hipStream_t stream) {
    const float* hr   = (const float*)d_in[0];
    const float* wk   = (const float*)d_in[1];
    const float* kb   = (const float*)d_in[2];
    const float* lb   = (const float*)d_in[3];
    const void*  mask = d_in[4];
    float* out = (float*)d_out;

    const size_t ATTN_B = (size_t)4 * 9 * F2 * 4;        // 1,806,336
    const size_t BLUR_B = (size_t)4 * DIM * HW2 * 2;     // 102,760,448 (bf16)
    int*   flag = (int*)d_ws;
    float* attn = (float*)((char*)d_ws + 256);           // fallback only
    unsigned short* blurh = (unsigned short*)((char*)d_ws + 256 + ATTN_B);
    const size_t need = 256 + ATTN_B + BLUR_B;           // ~104.6 MB

    if (ws_size >= need) {
        k_blur<<<4 * DIM, 256, 0, stream>>>(hr, blurh);
        k_fuse<<<4 * FINAL * 2, 512, 0, stream>>>(blurh, wk, kb, lb, mask, out);
    } else {
        k_detect<<<1, 1024, 0, stream>>>((const unsigned int*)mask, flag, (4 * 9 * F2) / 4);
        k_logits_fb<<<4 * FINAL, 512, 0, stream>>>(hr, wk, kb, lb, mask, flag, attn);
        k_out_fb<<<4 * FINAL, 512, 0, stream>>>(hr, attn, out);
    }
}

// Round 11
// 183.850 us; speedup vs baseline: 2.2374x; 2.2374x over previous
//
#include <hip/hip_runtime.h>
#include <cmath>

#define FINAL 112
#define HW    224
#define DIM   256
#define HW2   (HW*HW)       // 50176
#define F2    (FINAL*FINAL) // 12544

// Normalized separable 5-tap Gaussian, computed in double to match numpy
__device__ __forceinline__ void blur_weights(float fn[5]) {
    double fd[5]; double s = 0.0;
#pragma unroll
    for (int t = 0; t < 5; ++t) {
        double d = (double)(t - 2);
        fd[t] = exp(-1.4142135623730951 * d * d);
        s += fd[t];
    }
#pragma unroll
    for (int t = 0; t < 5; ++t) fn[t] = (float)(fd[t] / s);
}

// bf16 helpers. Pack via v_cvt_pk_bf16_f32 (gfx950 HW RTNE).
__device__ __forceinline__ unsigned int cvt_pk_bf16(float a, float b) {
    unsigned int r;
    asm("v_cvt_pk_bf16_f32 %0, %1, %2" : "=v"(r) : "v"(a), "v"(b));
    return r;
}
__device__ __forceinline__ float bflo(unsigned int q) { return __uint_as_float(q << 16); }
__device__ __forceinline__ float bfhi(unsigned int q) { return __uint_as_float(q & 0xffff0000u); }

// flag: 0=int32, 1=uint8, 2=float32, 3=int64
__device__ __forceinline__ float mask_val(const void* m, int flag, size_t idx) {
    if (flag == 0) return ((const int*)m)[idx] ? 1.0f : 0.0f;
    if (flag == 1) return ((const unsigned char*)m)[idx] ? 1.0f : 0.0f;
    if (flag == 2) return (((const float*)m)[idx] != 0.0f) ? 1.0f : 0.0f;
    return ((const long long*)m)[idx] ? 1.0f : 0.0f;
}

// fallback-path detect (fast path folds detection into k_softmax)
__global__ void k_detect(const unsigned int* __restrict__ m, int* __restrict__ flag, int nwords) {
    __shared__ int s_b123, s_3f, s_oddnz;
    if (threadIdx.x == 0) { s_b123 = 0; s_3f = 0; s_oddnz = 0; }
    __syncthreads();
    int b123 = 0, c3f = 0, oddnz = 0;
    for (int i = threadIdx.x; i < nwords; i += blockDim.x) {
        unsigned int u = m[i];
        if (u & 0xFFFFFF00u) b123++;
        if ((u >> 24) == 0x3Fu) c3f++;
        if ((i & 1) && u) oddnz++;
    }
    if (b123) atomicAdd(&s_b123, b123);
    if (c3f) atomicAdd(&s_3f, c3f);
    if (oddnz) atomicAdd(&s_oddnz, oddnz);
    __syncthreads();
    if (threadIdx.x == 0) {
        int f;
        if (s_b123 == 0) f = (s_oddnz == 0) ? 3 : 0;
        else if (s_3f > nwords / 8) f = 2;
        else f = 1;
        *flag = f;
    }
}

// ---------------- fast path ----------------

__device__ __forceinline__ float4 f4fma(float a, float4 x, float4 y) {
    return make_float4(fmaf(a, x.x, y.x), fmaf(a, x.y, y.y),
                       fmaf(a, x.z, y.z), fmaf(a, x.w, y.w));
}

// Register-streaming separable blur: zero LDS, zero barriers.
// Wave owns 28 rows (was 56): grid 2048 -> 32 waves/CU (2x TLP), +7% halo refetch.
// Per-output fmaf sequence identical to round-8 version (bit-identical output).
__launch_bounds__(256)
__global__ void k_blur(const float* __restrict__ hr, unsigned short* __restrict__ blurh) {
    const int bc   = blockIdx.x >> 1;
    const int half = blockIdx.x & 1;
    const int w = threadIdx.x >> 6, lane = threadIdx.x & 63;
    const bool act = (lane < 56);
    float fn[5]; blur_weights(fn);
    const float4* src = (const float4*)(hr + (size_t)bc * HW2);
    unsigned short* dst = blurh + (size_t)bc * HW2;
    const int rbase = half * 112 + w * 28 - 2;

    float4 z = make_float4(0.f, 0.f, 0.f, 0.f);
    float4 w0 = z, w1 = z, w2 = z, w3 = z, w4 = z;

#pragma unroll
    for (int p = 0; p < 4; ++p) {
        const int g = rbase + p;
        float4 v = z;
        if (g >= 0 && g < HW && act) v = src[(size_t)g * 56 + lane];
        w0 = w1; w1 = w2; w2 = w3; w3 = w4; w4 = v;
    }

#pragma unroll 4
    for (int i = 4; i < 32; ++i) {
        const int g = rbase + i;
        float4 v = z;
        if (g < HW && act) v = src[(size_t)g * 56 + lane];   // g >= 2 here
        w0 = w1; w1 = w2; w2 = w3; w3 = w4; w4 = v;

        float4 vb = z;
        vb = f4fma(fn[0], w0, vb);
        vb = f4fma(fn[1], w1, vb);
        vb = f4fma(fn[2], w2, vb);
        vb = f4fma(fn[3], w3, vb);
        vb = f4fma(fn[4], w4, vb);

        float lz = __shfl_up(vb.z, 1), lw = __shfl_up(vb.w, 1);
        if (lane == 0) { lz = 0.f; lw = 0.f; }
        float rx = __shfl_down(vb.x, 1), ry = __shfl_down(vb.y, 1);
        float win[8] = { lz, lw, vb.x, vb.y, vb.z, vb.w, rx, ry };
        float o[4];
#pragma unroll
        for (int j = 0; j < 4; ++j) {
            float s = 0.f;
#pragma unroll
            for (int t = 0; t < 5; ++t) s = fmaf(fn[t], win[j + t], s);
            o[j] = s;
        }
        if (act) {
            uint2 pk; pk.x = cvt_pk_bf16(o[0], o[1]); pk.y = cvt_pk_bf16(o[2], o[3]);
            *(uint2*)(dst + (size_t)(g - 2) * HW + 4 * lane) = pk;
        }
    }
}

// Partial logits: wave = (b, oy, 16-channel group). grid = 4*28*16 = 1792 x 256.
// (round-8 version: global wk reads, unroll 4)
__launch_bounds__(256)
__global__ void k_logits_part(const unsigned short* __restrict__ blurh,
                              const float* __restrict__ wk, float* __restrict__ part) {
    const int cg  = blockIdx.x & 15;
    const int rst = blockIdx.x >> 4;      // b*28 + oyq
    const int oyq = rst % 28, b = rst / 28;
    const int w = threadIdx.x >> 6, lane = threadIdx.x & 63;
    const int oy = oyq * 4 + w;
    const bool act = (lane < 56);
    const int row0 = 2 * oy - 1;

    float accE[9], accO[9];
#pragma unroll
    for (int o = 0; o < 9; ++o) { accE[o] = 0.f; accO[o] = 0.f; }

#pragma unroll 4
    for (int k = 0; k < 16; ++k) {
        const int c = cg * 16 + k;
        const unsigned short* base = blurh + ((size_t)(b * DIM + c)) * HW2;
        float tE[3][3], tO[3][3];
#pragma unroll
        for (int kh = 0; kh < 3; ++kh) {
            const int row = row0 + kh;
            uint2 q = make_uint2(0u, 0u);
            if (row >= 0 && act)
                q = *(const uint2*)(base + (size_t)row * HW + 4 * lane);
            float vx = bflo(q.x), vy = bfhi(q.x), vz = bflo(q.y), vw = bfhi(q.y);
            float pv = __shfl_up(vw, 1);
            if (lane == 0) pv = 0.f;
            tE[kh][0] = pv; tE[kh][1] = vx; tE[kh][2] = vy;
            tO[kh][0] = vy; tO[kh][1] = vz; tO[kh][2] = vw;
        }
        const float* wc = wk + (size_t)c * 9;
#pragma unroll
        for (int o = 0; o < 9; ++o) {
            const float* wo = wc + (size_t)o * (DIM * 9);
#pragma unroll
            for (int kh = 0; kh < 3; ++kh)
#pragma unroll
                for (int j = 0; j < 3; ++j) {
                    const float wvv = wo[kh * 3 + j];   // wave-uniform -> s_load
                    accE[o] = fmaf(wvv, tE[kh][j], accE[o]);
                    accO[o] = fmaf(wvv, tO[kh][j], accO[o]);
                }
        }
    }
    if (act) {
        float* pb = part + (((size_t)(cg * 4 + b)) * 9) * F2 + (size_t)oy * FINAL;
#pragma unroll
        for (int o = 0; o < 9; ++o)
            *(float2*)(pb + (size_t)o * F2 + 2 * lane) = make_float2(accE[o], accO[o]);
    }
}

// Combine 16 partials + bias + mask + softmax -> attn. In-block mask-encoding
// detection from the first 8KB. grid = 4*F2/256 = 196 exactly.
__launch_bounds__(256)
__global__ void k_softmax(const float* __restrict__ part, const float* __restrict__ kb,
                          const float* __restrict__ lb, const void* __restrict__ mask,
                          float* __restrict__ attn) {
    __shared__ int sb, sf, so;
    if (threadIdx.x == 0) { sb = 0; sf = 0; so = 0; }
    __syncthreads();
    const unsigned int* mw = (const unsigned int*)mask;
    int b123 = 0, c3f = 0, oddnz = 0;
    for (int i = threadIdx.x; i < 2048; i += 256) {
        unsigned int u = mw[i];
        if (u & 0xFFFFFF00u) b123++;
        if ((u >> 24) == 0x3Fu) c3f++;
        if ((i & 1) && u) oddnz++;
    }
    if (b123) atomicAdd(&sb, b123);
    if (c3f) atomicAdd(&sf, c3f);
    if (oddnz) atomicAdd(&so, oddnz);
    __syncthreads();
    int flag;
    if (sb == 0) flag = (so == 0) ? 3 : 0;
    else if (sf > 256) flag = 2;
    else flag = 1;

    const int idx = blockIdx.x * 256 + threadIdx.x;
    const int b = idx / F2, p = idx - b * F2;
    float l[9]; float mx = -3.4e38f;
#pragma unroll
    for (int o = 0; o < 9; ++o) {
        float s = 0.f;
#pragma unroll
        for (int g = 0; g < 16; ++g)
            s += part[(((size_t)(g * 4 + b)) * 9 + o) * F2 + p];
        size_t midx = ((size_t)b * 9 + o) * F2 + p;
        float lo = (s + kb[o]) * mask_val(mask, flag, midx) + lb[o];
        l[o] = lo; mx = fmaxf(mx, lo);
    }
    float sum = 0.f;
#pragma unroll
    for (int o = 0; o < 9; ++o) { l[o] = expf(l[o] - mx); sum += l[o]; }
    const float inv = 1.0f / sum;
#pragma unroll
    for (int o = 0; o < 9; ++o)
        attn[((size_t)b * 9 + o) * F2 + p] = l[o] * inv;
}

// Output: block = (b, oy, 32-channel group); 4 waves x 8 channels.
// grid = 4*112*8 = 3584 x 256.  (round-8 version)
__launch_bounds__(256)
__global__ void k_out(const unsigned short* __restrict__ blurh,
                      const float* __restrict__ attn, float* __restrict__ out) {
    const int cg  = blockIdx.x & 7;
    const int rst = blockIdx.x >> 3;      // b*112 + oy
    const int oy = rst % FINAL, b = rst / FINAL;
    const int w = threadIdx.x >> 6, lane = threadIdx.x & 63;
    const bool act = (lane < 56);
    const int row0 = 2 * oy - 1;

    __shared__ float sa[9][FINAL];
    for (int i = threadIdx.x; i < 9 * FINAL; i += 256) {
        int o = i / FINAL, x = i - o * FINAL;
        sa[o][x] = attn[((size_t)b * 9 + o) * F2 + (size_t)oy * FINAL + x];
    }
    __syncthreads();

    float aE[9], aO[9];
#pragma unroll
    for (int o = 0; o < 9; ++o) {
        float2 a = act ? *(const float2*)&sa[o][2 * lane] : make_float2(0.f, 0.f);
        aE[o] = a.x; aO[o] = a.y;
    }
#pragma unroll 4
    for (int k = 0; k < 8; ++k) {
        const int c = (cg << 5) + (w << 3) + k;
        const unsigned short* base = blurh + ((size_t)(b * DIM + c)) * HW2;
        float oE = 0.f, oO = 0.f;
#pragma unroll
        for (int kh = 0; kh < 3; ++kh) {
            const int row = row0 + kh;
            uint2 q = make_uint2(0u, 0u);
            if (row >= 0 && act)
                q = *(const uint2*)(base + (size_t)row * HW + 4 * lane);
            float vx = bflo(q.x), vy = bfhi(q.x), vz = bflo(q.y), vw = bfhi(q.y);
            float pv = __shfl_up(vw, 1);
            if (lane == 0) pv = 0.f;
            oE = fmaf(aE[kh * 3 + 0], pv, oE);
            oE = fmaf(aE[kh * 3 + 1], vx, oE);
            oE = fmaf(aE[kh * 3 + 2], vy, oE);
            oO = fmaf(aO[kh * 3 + 0], vy, oO);
            oO = fmaf(aO[kh * 3 + 1], vz, oO);
            oO = fmaf(aO[kh * 3 + 2], vw, oO);
        }
        if (act)
            *(float2*)(out + ((size_t)(b * DIM + c)) * F2 + (size_t)oy * FINAL + 2 * lane)
                = make_float2(oE, oO);
    }
}

// ---------------- fallback path (round-1, known-correct) ----------------

__launch_bounds__(512, 1)
__global__ void k_logits_fb(const float* __restrict__ hr, const float* __restrict__ wk,
                            const float* __restrict__ kb, const float* __restrict__ lb,
                            const void* __restrict__ mask, const int* __restrict__ flagp,
                            float* __restrict__ attn) {
    const int blk = blockIdx.x;
    const int b = blk / FINAL, oy = blk % FINAL;
    const int tid = threadIdx.x;
    const int half = tid >> 8;
    const int lane = tid & 255;
    __shared__ float sIn[2][7][HW];
    __shared__ float sV[2][3][HW + 4];
    __shared__ float sB[2][3][HW + 2];
    __shared__ float sW[2][81];
    __shared__ float sL[1008];
    float fn[5]; blur_weights(fn);
    if (lane < 3) {
        sV[half][lane][0] = 0.f; sV[half][lane][1] = 0.f;
        sV[half][lane][HW + 2] = 0.f; sV[half][lane][HW + 3] = 0.f;
        sB[half][lane][0] = 0.f; sB[half][lane][HW + 1] = 0.f;
    }
    float acc0 = 0.f, acc1 = 0.f;
    const int s1 = tid + 512;
    const int o0 = tid / FINAL, x0 = tid % FINAL;
    const int o1 = s1 / FINAL, x1 = s1 % FINAL;
    const bool has1 = (s1 < 9 * FINAL);
    for (int c0 = 0; c0 < DIM; c0 += 2) {
        const int c = c0 + half;
        const float* src = hr + ((size_t)(b * DIM + c)) * HW2;
        for (int i = lane; i < 7 * HW; i += 256) {
            int r = i / HW, x = i - r * HW;
            int g = 2 * oy - 3 + r;
            sIn[half][r][x] = (g >= 0 && g < HW) ? src[(size_t)g * HW + x] : 0.f;
        }
        if (lane < 81) {
            int o = lane / 9, kk = lane - o * 9;
            sW[half][lane] = wk[((size_t)(o * DIM + c)) * 9 + kk];
        }
        __syncthreads();
        if (lane < HW) {
#pragma unroll
            for (int j = 0; j < 3; ++j) {
                int by = 2 * oy - 1 + j;
                float v = 0.f;
#pragma unroll
                for (int t = 0; t < 5; ++t) v = fmaf(fn[t], sIn[half][j + t][lane], v);
                sV[half][j][lane + 2] = (by >= 0 && by < HW) ? v : 0.f;
            }
        }
        __syncthreads();
        if (lane < HW) {
#pragma unroll
            for (int j = 0; j < 3; ++j) {
                float v = 0.f;
#pragma unroll
                for (int t = 0; t < 5; ++t) v = fmaf(fn[t], sV[half][j][lane + t], v);
                sB[half][j][lane + 1] = v;
            }
        }
        __syncthreads();
#pragma unroll
        for (int cc = 0; cc < 2; ++cc) {
            const float* wv_ = sW[cc];
            float a0 = 0.f;
#pragma unroll
            for (int kh = 0; kh < 3; ++kh)
#pragma unroll
                for (int kw = 0; kw < 3; ++kw)
                    a0 = fmaf(sB[cc][kh][2 * x0 + kw], wv_[o0 * 9 + kh * 3 + kw], a0);
            acc0 += a0;
            if (has1) {
                float a1v = 0.f;
#pragma unroll
                for (int kh = 0; kh < 3; ++kh)
#pragma unroll
                    for (int kw = 0; kw < 3; ++kw)
                        a1v = fmaf(sB[cc][kh][2 * x1 + kw], wv_[o1 * 9 + kh * 3 + kw], a1v);
                acc1 += a1v;
            }
        }
        __syncthreads();
    }
    sL[tid] = acc0;
    if (has1) sL[s1] = acc1;
    __syncthreads();
    if (tid < FINAL) {
        const int flag = *flagp;
        float l[9]; float mx = -3.4e38f;
#pragma unroll
        for (int o = 0; o < 9; ++o) {
            size_t midx = (((size_t)b * 9 + o) * FINAL + oy) * FINAL + tid;
            float patch = sL[o * FINAL + tid] + kb[o];
            float lo = patch * mask_val(mask, flag, midx) + lb[o];
            l[o] = lo;
            mx = fmaxf(mx, lo);
        }
        float sum = 0.f;
#pragma unroll
        for (int o = 0; o < 9; ++o) { l[o] = expf(l[o] - mx); sum += l[o]; }
        float inv = 1.0f / sum;
#pragma unroll
        for (int o = 0; o < 9; ++o)
            attn[(((size_t)b * 9 + o) * FINAL + oy) * FINAL + tid] = l[o] * inv;
    }
}

__launch_bounds__(512, 1)
__global__ void k_out_fb(const float* __restrict__ hr, const float* __restrict__ attn,
                         float* __restrict__ out) {
    const int blk = blockIdx.x;
    const int b = blk / FINAL, oy = blk % FINAL;
    const int tid = threadIdx.x;
    const int half = tid >> 8;
    const int lane = tid & 255;
    __shared__ float sIn[2][7][HW];
    __shared__ float sV[2][3][HW + 4];
    __shared__ float sB[2][3][HW + 2];
    __shared__ float sA[9][FINAL];
    float fn[5]; blur_weights(fn);
    if (lane < 3) {
        sV[half][lane][0] = 0.f; sV[half][lane][1] = 0.f;
        sV[half][lane][HW + 2] = 0.f; sV[half][lane][HW + 3] = 0.f;
        sB[half][lane][0] = 0.f; sB[half][lane][HW + 1] = 0.f;
    }
    for (int i = tid; i < 9 * FINAL; i += 512) {
        int o = i / FINAL, x = i - o * FINAL;
        sA[o][x] = attn[(((size_t)b * 9 + o) * FINAL + oy) * FINAL + x];
    }
    for (int c0 = 0; c0 < DIM; c0 += 2) {
        const int c = c0 + half;
        const float* src = hr + ((size_t)(b * DIM + c)) * HW2;
        for (int i = lane; i < 7 * HW; i += 256) {
            int r = i / HW, x = i - r * HW;
            int g = 2 * oy - 3 + r;
            sIn[half][r][x] = (g >= 0 && g < HW) ? src[(size_t)g * HW + x] : 0.f;
        }
        __syncthreads();
        if (lane < HW) {
#pragma unroll
            for (int j = 0; j < 3; ++j) {
                int by = 2 * oy - 1 + j;
                float v = 0.f;
#pragma unroll
                for (int t = 0; t < 5; ++t) v = fmaf(fn[t], sIn[half][j + t][lane], v);
                sV[half][j][lane + 2] = (by >= 0 && by < HW) ? v : 0.f;
            }
        }
        __syncthreads();
        if (lane < HW) {
#pragma unroll
            for (int j = 0; j < 3; ++j) {
                float v = 0.f;
#pragma unroll
                for (int t = 0; t < 5; ++t) v = fmaf(fn[t], sV[half][j][lane + t], v);
                sB[half][j][lane + 1] = v;
            }
        }
        __syncthreads();
        if (lane < FINAL) {
            float a = 0.f;
#pragma unroll
            for (int kh = 0; kh < 3; ++kh)
#pragma unroll
                for (int kw = 0; kw < 3; ++kw)
                    a = fmaf(sA[kh * 3 + kw][lane], sB[half][kh][2 * lane + kw], a);
            out[(((size_t)(b * DIM + c)) * FINAL + oy) * FINAL + lane] = a;
        }
    }
}

extern "C" void kernel_launch(void* const* d_in, const int* in_sizes, int n_in,
                              void* d_out, int out_size, void* d_ws, size_t ws_size,
                              hipStream_t stream) {
    const float* hr   = (const float*)d_in[0];
    const float* wk   = (const float*)d_in[1];
    const float* kb   = (const float*)d_in[2];
    const float* lb   = (const float*)d_in[3];
    const void*  mask = d_in[4];
    float* out = (float*)d_out;

    const size_t ATTN_B = (size_t)4 * 9 * F2 * 4;        // 1,806,336
    const size_t PART_B = ATTN_B * 16;                   // 28,901,376
    const size_t BLUR_B = (size_t)4 * DIM * HW2 * 2;     // 102,760,448 (bf16)
    int*   flag = (int*)d_ws;
    float* attn = (float*)((char*)d_ws + 256);
    float* part = (float*)((char*)d_ws + 256 + ATTN_B);
    unsigned short* blurh = (unsigned short*)((char*)d_ws + 256 + ATTN_B + PART_B);
    const size_t need = 256 + ATTN_B + PART_B + BLUR_B;  // ~131.5 MB

    if (ws_size >= need) {
        k_blur<<<4 * DIM * 2, 256, 0, stream>>>(hr, blurh);
        k_logits_part<<<4 * 28 * 16, 256, 0, stream>>>(blurh, wk, part);
        k_softmax<<<(4 * F2) / 256, 256, 0, stream>>>(part, kb, lb, mask, attn);
        k_out<<<4 * FINAL * 8, 256, 0, stream>>>(blurh, attn, out);
    } else {
        k_detect<<<1, 1024, 0, stream>>>((const unsigned int*)mask, flag, (4 * 9 * F2) / 4);
        k_logits_fb<<<4 * FINAL, 512, 0, stream>>>(hr, wk, kb, lb, mask, flag, attn);
        k_out_fb<<<4 * FINAL, 512, 0, stream>>>(hr, attn, out);
    }
}